// Round 20
// baseline (79.142 us; speedup 1.0000x reference)
//
#include <hip/hip_runtime.h>

#define DD 8
#define HH 512
#define WW 512
#define HW (HH * WW)
#define DHW (DD * HW)
#define BC 8
#define NITERS 5
#define TCAP 512u

typedef float vf4 __attribute__((ext_vector_type(4)));

__device__ __forceinline__ float max3f(float a, float b, float c) {
    return fmaxf(fmaxf(a, b), c);
}

// Solve the 3x3 symmetric system at interior position (di,hi,wi) of one (b,c) volume.
__device__ __forceinline__ bool solve_at(const float* __restrict__ xb,
                                         int di, int hi, int wi,
                                         float& sx, float& sy, float& ss, float& gds)
{
    const float* p = xb + (size_t)di * HW + (size_t)hi * WW + wi;
    float v   = p[0];
    float xpw = p[1],        xmw = p[-1];
    float xph = p[WW],       xmh = p[-WW];
    float xpd = p[HW],       xmd = p[-HW];
    float g1  = p[WW + 1],   g2  = p[WW - 1],   g3 = p[-WW + 1],  g4 = p[-WW - 1];
    float h1  = p[HW + 1],   h2  = p[HW - 1],   h3 = p[-HW + 1],  h4 = p[-HW - 1];
    float i1  = p[HW + WW],  i2  = p[HW - WW],  i3 = p[-HW + WW], i4 = p[-HW - WW];

    float gx = 0.5f * (xpw - xmw);
    float gy = 0.5f * (xph - xmh);
    float gs = 0.5f * (xpd - xmd);
    float dxx = xpw + xmw - 2.0f * v;
    float dyy = xph + xmh - 2.0f * v;
    float dss = xpd + xmd - 2.0f * v;
    float dxy = 0.25f * (g1 - g2 - g3 + g4);
    float dxs = 0.25f * (h1 - h2 - h3 + h4);
    float dys = 0.25f * (i1 - i2 - i3 + i4);

    float r0 = -gx, r1 = -gy, r2 = -gs;
    float cf00 = dyy * dss - dys * dys;
    float cf01 = dxy * dss - dys * dxs;
    float cf02 = dxy * dys - dyy * dxs;
    float det  = dxx * cf00 - dxy * cf01 + dxs * cf02;
    if (!(fabsf(det) > 1e-7f)) return false;

    float t0 = r1 * dss - dys * r2;
    float t1 = r1 * dys - dyy * r2;
    float t2 = dxy * r2 - r1 * dxs;
    float t3 = dyy * r2 - r1 * dys;
    sx = (r0 * cf00 - dxy * t0 + dxs * t1) / det;
    sy = (dxx * t0 - r0 * cf01 + dxs * t2) / det;
    ss = (dxx * t3 - dxy * t2 + r0 * cf02) / det;
    gds = gx * sx + gy * sy + gs * ss;
    return true;
}

// Edge values via intra-wave shuffle with 1-lane masked fixup loads at wave seams.
#define COMPUTE(d, M, CEN) {                                                               \
    const float* s  = xb + (size_t)(d) * HW;                                               \
    const float* r0 = s + (size_t)hm * WW;                                                 \
    const float* r1 = s + (size_t)h  * WW;                                                 \
    const float* r2 = s + (size_t)hp * WW;                                                 \
    vf4 va = *(const vf4*)(r0 + w0);                                                       \
    vf4 vb = *(const vf4*)(r1 + w0);                                                       \
    vf4 vc = *(const vf4*)(r2 + w0);                                                       \
    float la = __shfl_up(va.w, 1, 64);                                                     \
    float lb = __shfl_up(vb.w, 1, 64);                                                     \
    float lc = __shfl_up(vc.w, 1, 64);                                                     \
    if (lane == 0) {                                                                       \
        la = w0 ? r0[w0 - 1] : va.x;                                                       \
        lb = w0 ? r1[w0 - 1] : vb.x;                                                       \
        lc = w0 ? r2[w0 - 1] : vc.x;                                                       \
    }                                                                                      \
    float ra = __shfl_down(va.x, 1, 64);                                                   \
    float rb = __shfl_down(vb.x, 1, 64);                                                   \
    float rc = __shfl_down(vc.x, 1, 64);                                                   \
    if (lane == 63) {                                                                      \
        ra = (w0 < 508) ? r0[w0 + 4] : va.w;                                               \
        rb = (w0 < 508) ? r1[w0 + 4] : vb.w;                                               \
        rc = (w0 < 508) ? r2[w0 + 4] : vc.w;                                               \
    }                                                                                      \
    (M).x = max3f(max3f(la, va.x, va.y), max3f(lb, vb.x, vb.y), max3f(lc, vc.x, vc.y));    \
    (M).y = max3f(max3f(va.x, va.y, va.z), max3f(vb.x, vb.y, vb.z), max3f(vc.x, vc.y, vc.z)); \
    (M).z = max3f(max3f(va.y, va.z, va.w), max3f(vb.y, vb.z, vb.w), max3f(vc.y, vc.z, vc.w)); \
    (M).w = max3f(max3f(va.z, va.w, ra), max3f(vb.z, vb.w, rb), max3f(vc.z, vc.w, rc));    \
    (CEN) = vb; }

// flags-only: record NMS bits, push maxima local ids (u16), save per-(wave,d) base
#define FLAG(d, MP, MC, MN) {                                                              \
    float mx0 = max3f((MP).x, (MC).x, (MN).x);                                             \
    float mx1 = max3f((MP).y, (MC).y, (MN).y);                                             \
    float mx2 = max3f((MP).z, (MC).z, (MN).z);                                             \
    float mx3 = max3f((MP).w, (MC).w, (MN).w);                                             \
    bool n0 = cen[d].x == mx0, n1 = cen[d].y == mx1, n2 = cen[d].z == mx2, n3 = cen[d].w == mx3; \
    nmsmask |= ((n0?1u:0u)|(n1?2u:0u)|(n2?4u:0u)|(n3?8u:0u)) << (4*(d));                   \
    unsigned long long b0 = __ballot(n0), b1 = __ballot(n1), b2 = __ballot(n2), b3 = __ballot(n3); \
    unsigned tot = (unsigned)(__popcll(b0) + __popcll(b1) + __popcll(b2) + __popcll(b3));  \
    unsigned base = 0;                                                                     \
    if (tot) {                                                                             \
        if (lane == 0) base = atomicAdd(&ls_count, tot);                                   \
        base = (unsigned)__shfl((int)base, 0, 64);                                         \
        unsigned long long below = ((unsigned long long)1 << lane) - 1;                    \
        unsigned vix = (unsigned)(((d) * 2 + rrow) * WW + w0);                             \
        unsigned o = base, p;                                                              \
        p = o + (unsigned)__popcll(b0 & below); if (n0 && p < TCAP) ls_list[p] = (unsigned short)vix;       \
        o += (unsigned)__popcll(b0);                                                       \
        p = o + (unsigned)__popcll(b1 & below); if (n1 && p < TCAP) ls_list[p] = (unsigned short)(vix + 1); \
        o += (unsigned)__popcll(b1);                                                       \
        p = o + (unsigned)__popcll(b2 & below); if (n2 && p < TCAP) ls_list[p] = (unsigned short)(vix + 2); \
        o += (unsigned)__popcll(b2);                                                       \
        p = o + (unsigned)__popcll(b3 & below); if (n3 && p < TCAP) ls_list[p] = (unsigned short)(vix + 3); \
    }                                                                                      \
    if (lane == 0) ls_wbase[wid * 8 + (d)] = (unsigned short)base; }

__global__ __launch_bounds__(256) void fused17_kernel(const float* __restrict__ x,
                                                      float* __restrict__ out)
{
    __shared__ unsigned ls_count;
    __shared__ unsigned short ls_list[TCAP];   //  1 KB: slot -> local voxel id
    __shared__ unsigned short ls_wbase[4 * 8]; // 64 B: per-(wave,d) slot base
    __shared__ vf4 ls_tab[TCAP];               //  8 KB: {cs, cx, cy, 0.5*gds}

    if (threadIdx.x == 0) ls_count = 0;
    __syncthreads();

    // XCD-aware swizzle: each XCD gets one contiguous run of 256 blocks
    // = exactly one (b,c) volume -> halo rows are local-L2 hits.
    int b = (blockIdx.x & 7) * 256 + (blockIdx.x >> 3);
    int tid = b * 256 + threadIdx.x;
    int w4 = tid & 127;
    int h  = (tid >> 7) & 511;
    int bc = tid >> 16;
    int w0 = w4 << 2;
    int lane = threadIdx.x & 63;
    int wid  = threadIdx.x >> 6;     // wave id 0..3
    int rrow = threadIdx.x >> 7;     // 0/1: row within block
    int h0blk = h - rrow;            // block base row (uniform)

    const float* xb = x + (size_t)bc * DHW;
    float* ybase = out + (size_t)(BC * 3) * DHW;
    int hm = h ? h - 1 : 0, hp = h < 511 ? h + 1 : 511;

    // ---- phase 1: streaming NMS, flags only ----
    vf4 cen[DD];
    unsigned nmsmask = 0;
    vf4 m0, m1, m2r;
    COMPUTE(0, m0, cen[0]);
    COMPUTE(1, m1, cen[1]);
    FLAG(0, m0, m0, m1);
    COMPUTE(2, m2r, cen[2]);
    FLAG(1, m0, m1, m2r);
    COMPUTE(3, m0, cen[3]);
    FLAG(2, m1, m2r, m0);
    COMPUTE(4, m1, cen[4]);
    FLAG(3, m2r, m0, m1);
    COMPUTE(5, m2r, cen[5]);
    FLAG(4, m0, m1, m2r);
    COMPUTE(6, m0, cen[6]);
    FLAG(5, m1, m2r, m0);
    COMPUTE(7, m1, cen[7]);
    FLAG(6, m2r, m0, m1);
    FLAG(7, m0, m1, m1);

    // ---- phase 2: refine block's maxima; ls_tab written UNCONDITIONALLY ----
    __syncthreads();
    unsigned n = ls_count;
    if (n > TCAP) n = TCAP;

    for (unsigned i = threadIdx.x; i < n; i += 256) {
        unsigned v = ls_list[i];
        int rw = v & 511;
        int rr = (v >> 9) & 1;
        int rd = v >> 10;
        int rh = h0blk + rr;

        int cd = rd, ch = rh, cw = rw;
        bool valid = true;
        float shx = 0.f, shy = 0.f, shs = 0.f, gds = 0.f;
        for (int it = 0; it < NITERS; ++it) {
            int di = cd < 1 ? 1 : (cd > DD - 2 ? DD - 2 : cd);
            int hi = ch < 1 ? 1 : (ch > HH - 2 ? HH - 2 : ch);
            int wi = cw < 1 ? 1 : (cw > WW - 2 ? WW - 2 : cw);
            float sx, sy, ss, g;
            if (!solve_at(xb, di, hi, wi, sx, sy, ss, g)) { valid = false; break; }
            shx = sx; shy = sy; shs = ss; gds = g;
            int mvw = (fabsf(sx) > 0.6f) ? (sx > 0.f ? 1 : -1) : 0;
            int mvh = (fabsf(sy) > 0.6f) ? (sy > 0.f ? 1 : -1) : 0;
            int mvd = (fabsf(ss) > 0.6f) ? (ss > 0.f ? 1 : -1) : 0;
            if ((mvw | mvh | mvd) == 0) break;
            cw += mvw; ch += mvh; cd += mvd;
            int ad = cd - rd; if (ad < 0) ad = -ad;
            int ah = ch - rh; if (ah < 0) ah = -ah;
            int aw = cw - rw; if (aw < 0) aw = -aw;
            if (ad > 1 || ah > 1 || aw > 1) { valid = false; break; }
        }
        vf4 t;
        if (valid) {
            t.x = (float)cd + shs; t.y = (float)cw + shx;
            t.z = (float)ch + shy; t.w = 0.5f * gds;
        } else {
            t.x = (float)rd; t.y = (float)rw; t.z = (float)rh; t.w = 0.0f;
        }
        ls_tab[i] = t;
    }

    // ---- phase 3: single-pass stores; cs+cx+y plain (L2 write-back), cy NT ----
    __syncthreads();

    #pragma unroll
    for (int d = 0; d < DD; ++d) {
        unsigned fl = (nmsmask >> (4 * d)) & 15u;
        bool n0 = fl & 1u, n1 = fl & 2u, n2 = fl & 4u, n3 = fl & 8u;
        vf4 csv = { (float)d, (float)d, (float)d, (float)d };
        vf4 cxv = { (float)w0, (float)(w0 + 1), (float)(w0 + 2), (float)(w0 + 3) };
        vf4 cyv = { (float)h, (float)h, (float)h, (float)h };
        vf4 yv  = { cen[d].x + (n0 ? 10.0f : 0.0f),
                    cen[d].y + (n1 ? 10.0f : 0.0f),
                    cen[d].z + (n2 ? 10.0f : 0.0f),
                    cen[d].w + (n3 ? 10.0f : 0.0f) };
        // wave-collective ballots reproduce phase-1 slot assignment exactly
        unsigned long long b0 = __ballot(n0), b1 = __ballot(n1), b2 = __ballot(n2), b3 = __ballot(n3);
        if (fl) {
            unsigned long long below = ((unsigned long long)1 << lane) - 1;
            unsigned basew = ls_wbase[wid * 8 + d];
            unsigned c0 = (unsigned)__popcll(b0), c1 = (unsigned)__popcll(b1), c2 = (unsigned)__popcll(b2);
            unsigned p0 = basew + (unsigned)__popcll(b0 & below);
            unsigned p1 = basew + c0 + (unsigned)__popcll(b1 & below);
            unsigned p2 = basew + c0 + c1 + (unsigned)__popcll(b2 & below);
            unsigned p3 = basew + c0 + c1 + c2 + (unsigned)__popcll(b3 & below);
            if (n0 && p0 < TCAP) { vf4 t = ls_tab[p0]; csv.x = t.x; cxv.x = t.y; cyv.x = t.z; yv.x += t.w; }
            if (n1 && p1 < TCAP) { vf4 t = ls_tab[p1]; csv.y = t.x; cxv.y = t.y; cyv.y = t.z; yv.y += t.w; }
            if (n2 && p2 < TCAP) { vf4 t = ls_tab[p2]; csv.z = t.x; cxv.z = t.y; cyv.z = t.z; yv.z += t.w; }
            if (n3 && p3 < TCAP) { vf4 t = ls_tab[p3]; csv.w = t.x; cxv.w = t.y; cyv.w = t.z; yv.w += t.w; }
        }
        size_t rowoff = (size_t)d * HW + (size_t)h * WW + w0;
        *(vf4*)(out + ((size_t)bc * 3 + 0) * DHW + rowoff) = csv;   // plain
        *(vf4*)(out + ((size_t)bc * 3 + 1) * DHW + rowoff) = cxv;   // plain
        __builtin_nontemporal_store(cyv, (vf4*)(out + ((size_t)bc * 3 + 2) * DHW + rowoff));
        *(vf4*)(ybase + (size_t)bc * DHW + rowoff) = yv;            // plain
    }
}

extern "C" void kernel_launch(void* const* d_in, const int* in_sizes, int n_in,
                              void* d_out, int out_size, void* d_ws, size_t ws_size,
                              hipStream_t stream)
{
    const float* x = (const float*)d_in[0];
    float* out = (float*)d_out;
    int total = BC * HH * (WW / 4);              // 524288 threads -> 2048 blocks
    hipLaunchKernelGGL(fused17_kernel, dim3(total / 256), dim3(256), 0, stream, x, out);
}

// Round 21
// 78.103 us; speedup vs baseline: 1.0133x; 1.0133x over previous
//
#include <hip/hip_runtime.h>

#define DD 8
#define HH 512
#define WW 512
#define HW (HH * WW)
#define DHW (DD * HW)
#define BC 8
#define NITERS 5
#define TCAP 512u

typedef float vf4 __attribute__((ext_vector_type(4)));

__device__ __forceinline__ float max3f(float a, float b, float c) {
    return fmaxf(fmaxf(a, b), c);
}

// Solve the 3x3 symmetric system at interior position (di,hi,wi) of one (b,c) volume.
__device__ __forceinline__ bool solve_at(const float* __restrict__ xb,
                                         int di, int hi, int wi,
                                         float& sx, float& sy, float& ss, float& gds)
{
    const float* p = xb + (size_t)di * HW + (size_t)hi * WW + wi;
    float v   = p[0];
    float xpw = p[1],        xmw = p[-1];
    float xph = p[WW],       xmh = p[-WW];
    float xpd = p[HW],       xmd = p[-HW];
    float g1  = p[WW + 1],   g2  = p[WW - 1],   g3 = p[-WW + 1],  g4 = p[-WW - 1];
    float h1  = p[HW + 1],   h2  = p[HW - 1],   h3 = p[-HW + 1],  h4 = p[-HW - 1];
    float i1  = p[HW + WW],  i2  = p[HW - WW],  i3 = p[-HW + WW], i4 = p[-HW - WW];

    float gx = 0.5f * (xpw - xmw);
    float gy = 0.5f * (xph - xmh);
    float gs = 0.5f * (xpd - xmd);
    float dxx = xpw + xmw - 2.0f * v;
    float dyy = xph + xmh - 2.0f * v;
    float dss = xpd + xmd - 2.0f * v;
    float dxy = 0.25f * (g1 - g2 - g3 + g4);
    float dxs = 0.25f * (h1 - h2 - h3 + h4);
    float dys = 0.25f * (i1 - i2 - i3 + i4);

    float r0 = -gx, r1 = -gy, r2 = -gs;
    float cf00 = dyy * dss - dys * dys;
    float cf01 = dxy * dss - dys * dxs;
    float cf02 = dxy * dys - dyy * dxs;
    float det  = dxx * cf00 - dxy * cf01 + dxs * cf02;
    if (!(fabsf(det) > 1e-7f)) return false;

    float t0 = r1 * dss - dys * r2;
    float t1 = r1 * dys - dyy * r2;
    float t2 = dxy * r2 - r1 * dxs;
    float t3 = dyy * r2 - r1 * dys;
    sx = (r0 * cf00 - dxy * t0 + dxs * t1) / det;
    sy = (dxx * t0 - r0 * cf01 + dxs * t2) / det;
    ss = (dxx * t3 - dxy * t2 + r0 * cf02) / det;
    gds = gx * sx + gy * sy + gs * ss;
    return true;
}

// Edge values via intra-wave shuffle with 1-lane masked fixup loads at wave seams.
#define COMPUTE(d, M, CEN) {                                                               \
    const float* s  = xb + (size_t)(d) * HW;                                               \
    const float* r0 = s + (size_t)hm * WW;                                                 \
    const float* r1 = s + (size_t)h  * WW;                                                 \
    const float* r2 = s + (size_t)hp * WW;                                                 \
    vf4 va = *(const vf4*)(r0 + w0);                                                       \
    vf4 vb = *(const vf4*)(r1 + w0);                                                       \
    vf4 vc = *(const vf4*)(r2 + w0);                                                       \
    float la = __shfl_up(va.w, 1, 64);                                                     \
    float lb = __shfl_up(vb.w, 1, 64);                                                     \
    float lc = __shfl_up(vc.w, 1, 64);                                                     \
    if (lane == 0) {                                                                       \
        la = w0 ? r0[w0 - 1] : va.x;                                                       \
        lb = w0 ? r1[w0 - 1] : vb.x;                                                       \
        lc = w0 ? r2[w0 - 1] : vc.x;                                                       \
    }                                                                                      \
    float ra = __shfl_down(va.x, 1, 64);                                                   \
    float rb = __shfl_down(vb.x, 1, 64);                                                   \
    float rc = __shfl_down(vc.x, 1, 64);                                                   \
    if (lane == 63) {                                                                      \
        ra = (w0 < 508) ? r0[w0 + 4] : va.w;                                               \
        rb = (w0 < 508) ? r1[w0 + 4] : vb.w;                                               \
        rc = (w0 < 508) ? r2[w0 + 4] : vc.w;                                               \
    }                                                                                      \
    (M).x = max3f(max3f(la, va.x, va.y), max3f(lb, vb.x, vb.y), max3f(lc, vc.x, vc.y));    \
    (M).y = max3f(max3f(va.x, va.y, va.z), max3f(vb.x, vb.y, vb.z), max3f(vc.x, vc.y, vc.z)); \
    (M).z = max3f(max3f(va.y, va.z, va.w), max3f(vb.y, vb.z, vb.w), max3f(vc.y, vc.z, vc.w)); \
    (M).w = max3f(max3f(va.z, va.w, ra), max3f(vb.z, vb.w, rb), max3f(vc.z, vc.w, rc));    \
    (CEN) = vb; }

// flags-only: record NMS bits, push maxima local ids (u16), save per-(wave,d) base
#define FLAG(d, MP, MC, MN) {                                                              \
    float mx0 = max3f((MP).x, (MC).x, (MN).x);                                             \
    float mx1 = max3f((MP).y, (MC).y, (MN).y);                                             \
    float mx2 = max3f((MP).z, (MC).z, (MN).z);                                             \
    float mx3 = max3f((MP).w, (MC).w, (MN).w);                                             \
    bool n0 = cen[d].x == mx0, n1 = cen[d].y == mx1, n2 = cen[d].z == mx2, n3 = cen[d].w == mx3; \
    nmsmask |= ((n0?1u:0u)|(n1?2u:0u)|(n2?4u:0u)|(n3?8u:0u)) << (4*(d));                   \
    unsigned long long b0 = __ballot(n0), b1 = __ballot(n1), b2 = __ballot(n2), b3 = __ballot(n3); \
    unsigned tot = (unsigned)(__popcll(b0) + __popcll(b1) + __popcll(b2) + __popcll(b3));  \
    unsigned base = 0;                                                                     \
    if (tot) {                                                                             \
        if (lane == 0) base = atomicAdd(&ls_count, tot);                                   \
        base = (unsigned)__shfl((int)base, 0, 64);                                         \
        unsigned long long below = ((unsigned long long)1 << lane) - 1;                    \
        unsigned vix = (unsigned)(((d) * 2 + rrow) * WW + w0);                             \
        unsigned o = base, p;                                                              \
        p = o + (unsigned)__popcll(b0 & below); if (n0 && p < TCAP) ls_list[p] = (unsigned short)vix;       \
        o += (unsigned)__popcll(b0);                                                       \
        p = o + (unsigned)__popcll(b1 & below); if (n1 && p < TCAP) ls_list[p] = (unsigned short)(vix + 1); \
        o += (unsigned)__popcll(b1);                                                       \
        p = o + (unsigned)__popcll(b2 & below); if (n2 && p < TCAP) ls_list[p] = (unsigned short)(vix + 2); \
        o += (unsigned)__popcll(b2);                                                       \
        p = o + (unsigned)__popcll(b3 & below); if (n3 && p < TCAP) ls_list[p] = (unsigned short)(vix + 3); \
    }                                                                                      \
    if (lane == 0) ls_wbase[wid * 8 + (d)] = (unsigned short)base; }

__global__ __launch_bounds__(256) void fused18_kernel(const float* __restrict__ x,
                                                      float* __restrict__ out)
{
    __shared__ unsigned ls_count;
    __shared__ unsigned short ls_list[TCAP];   //  1 KB: slot -> local voxel id
    __shared__ unsigned short ls_wbase[4 * 8]; // 64 B: per-(wave,d) slot base
    __shared__ vf4 ls_tab[TCAP];               //  8 KB: {cs, cx, cy, 0.5*gds}

    if (threadIdx.x == 0) ls_count = 0;
    __syncthreads();

    // XCD-aware swizzle: each XCD gets one contiguous run of 256 blocks
    // = exactly one (b,c) volume -> halo rows are local-L2 hits.
    int b = (blockIdx.x & 7) * 256 + (blockIdx.x >> 3);
    int tid = b * 256 + threadIdx.x;
    int w4 = tid & 127;
    int h  = (tid >> 7) & 511;
    int bc = tid >> 16;
    int w0 = w4 << 2;
    int lane = threadIdx.x & 63;
    int wid  = threadIdx.x >> 6;     // wave id 0..3
    int rrow = threadIdx.x >> 7;     // 0/1: row within block
    int h0blk = h - rrow;            // block base row (uniform)

    const float* xb = x + (size_t)bc * DHW;
    float* ybase = out + (size_t)(BC * 3) * DHW;
    int hm = h ? h - 1 : 0, hp = h < 511 ? h + 1 : 511;

    // ---- phase 1: streaming NMS, flags only ----
    vf4 cen[DD];
    unsigned nmsmask = 0;
    vf4 m0, m1, m2r;
    COMPUTE(0, m0, cen[0]);
    COMPUTE(1, m1, cen[1]);
    FLAG(0, m0, m0, m1);
    COMPUTE(2, m2r, cen[2]);
    FLAG(1, m0, m1, m2r);
    COMPUTE(3, m0, cen[3]);
    FLAG(2, m1, m2r, m0);
    COMPUTE(4, m1, cen[4]);
    FLAG(3, m2r, m0, m1);
    COMPUTE(5, m2r, cen[5]);
    FLAG(4, m0, m1, m2r);
    COMPUTE(6, m0, cen[6]);
    FLAG(5, m1, m2r, m0);
    COMPUTE(7, m1, cen[7]);
    FLAG(6, m2r, m0, m1);
    FLAG(7, m0, m1, m1);

    // ---- phase 2: refine block's maxima; ls_tab written UNCONDITIONALLY ----
    __syncthreads();
    unsigned n = ls_count;
    if (n > TCAP) n = TCAP;

    for (unsigned i = threadIdx.x; i < n; i += 256) {
        unsigned v = ls_list[i];
        int rw = v & 511;
        int rr = (v >> 9) & 1;
        int rd = v >> 10;
        int rh = h0blk + rr;

        int cd = rd, ch = rh, cw = rw;
        bool valid = true;
        float shx = 0.f, shy = 0.f, shs = 0.f, gds = 0.f;
        for (int it = 0; it < NITERS; ++it) {
            int di = cd < 1 ? 1 : (cd > DD - 2 ? DD - 2 : cd);
            int hi = ch < 1 ? 1 : (ch > HH - 2 ? HH - 2 : ch);
            int wi = cw < 1 ? 1 : (cw > WW - 2 ? WW - 2 : cw);
            float sx, sy, ss, g;
            if (!solve_at(xb, di, hi, wi, sx, sy, ss, g)) { valid = false; break; }
            shx = sx; shy = sy; shs = ss; gds = g;
            int mvw = (fabsf(sx) > 0.6f) ? (sx > 0.f ? 1 : -1) : 0;
            int mvh = (fabsf(sy) > 0.6f) ? (sy > 0.f ? 1 : -1) : 0;
            int mvd = (fabsf(ss) > 0.6f) ? (ss > 0.f ? 1 : -1) : 0;
            if ((mvw | mvh | mvd) == 0) break;
            cw += mvw; ch += mvh; cd += mvd;
            int ad = cd - rd; if (ad < 0) ad = -ad;
            int ah = ch - rh; if (ah < 0) ah = -ah;
            int aw = cw - rw; if (aw < 0) aw = -aw;
            if (ad > 1 || ah > 1 || aw > 1) { valid = false; break; }
        }
        vf4 t;
        if (valid) {
            t.x = (float)cd + shs; t.y = (float)cw + shx;
            t.z = (float)ch + shy; t.w = 0.5f * gds;
        } else {
            t.x = (float)rd; t.y = (float)rw; t.z = (float)rh; t.w = 0.0f;
        }
        ls_tab[i] = t;
    }

    // ---- phase 3: single-pass stores; cs+y plain (L2 write-back), cx+cy NT ----
    // (measured optimum of the NT/plain sweep: 0%->80.1, 25%->78.6, 50%->78.1,
    //  75%->79.1, 100%->104.2 us)
    __syncthreads();

    #pragma unroll
    for (int d = 0; d < DD; ++d) {
        unsigned fl = (nmsmask >> (4 * d)) & 15u;
        bool n0 = fl & 1u, n1 = fl & 2u, n2 = fl & 4u, n3 = fl & 8u;
        vf4 csv = { (float)d, (float)d, (float)d, (float)d };
        vf4 cxv = { (float)w0, (float)(w0 + 1), (float)(w0 + 2), (float)(w0 + 3) };
        vf4 cyv = { (float)h, (float)h, (float)h, (float)h };
        vf4 yv  = { cen[d].x + (n0 ? 10.0f : 0.0f),
                    cen[d].y + (n1 ? 10.0f : 0.0f),
                    cen[d].z + (n2 ? 10.0f : 0.0f),
                    cen[d].w + (n3 ? 10.0f : 0.0f) };
        // wave-collective ballots reproduce phase-1 slot assignment exactly
        unsigned long long b0 = __ballot(n0), b1 = __ballot(n1), b2 = __ballot(n2), b3 = __ballot(n3);
        if (fl) {
            unsigned long long below = ((unsigned long long)1 << lane) - 1;
            unsigned basew = ls_wbase[wid * 8 + d];
            unsigned c0 = (unsigned)__popcll(b0), c1 = (unsigned)__popcll(b1), c2 = (unsigned)__popcll(b2);
            unsigned p0 = basew + (unsigned)__popcll(b0 & below);
            unsigned p1 = basew + c0 + (unsigned)__popcll(b1 & below);
            unsigned p2 = basew + c0 + c1 + (unsigned)__popcll(b2 & below);
            unsigned p3 = basew + c0 + c1 + c2 + (unsigned)__popcll(b3 & below);
            if (n0 && p0 < TCAP) { vf4 t = ls_tab[p0]; csv.x = t.x; cxv.x = t.y; cyv.x = t.z; yv.x += t.w; }
            if (n1 && p1 < TCAP) { vf4 t = ls_tab[p1]; csv.y = t.x; cxv.y = t.y; cyv.y = t.z; yv.y += t.w; }
            if (n2 && p2 < TCAP) { vf4 t = ls_tab[p2]; csv.z = t.x; cxv.z = t.y; cyv.z = t.z; yv.z += t.w; }
            if (n3 && p3 < TCAP) { vf4 t = ls_tab[p3]; csv.w = t.x; cxv.w = t.y; cyv.w = t.z; yv.w += t.w; }
        }
        size_t rowoff = (size_t)d * HW + (size_t)h * WW + w0;
        *(vf4*)(out + ((size_t)bc * 3 + 0) * DHW + rowoff) = csv;   // plain
        __builtin_nontemporal_store(cxv, (vf4*)(out + ((size_t)bc * 3 + 1) * DHW + rowoff));
        __builtin_nontemporal_store(cyv, (vf4*)(out + ((size_t)bc * 3 + 2) * DHW + rowoff));
        *(vf4*)(ybase + (size_t)bc * DHW + rowoff) = yv;            // plain
    }
}

extern "C" void kernel_launch(void* const* d_in, const int* in_sizes, int n_in,
                              void* d_out, int out_size, void* d_ws, size_t ws_size,
                              hipStream_t stream)
{
    const float* x = (const float*)d_in[0];
    float* out = (float*)d_out;
    int total = BC * HH * (WW / 4);              // 524288 threads -> 2048 blocks
    hipLaunchKernelGGL(fused18_kernel, dim3(total / 256), dim3(256), 0, stream, x, out);
}